// Round 15
// baseline (18921.886 us; speedup 1.0000x reference)
//
#include <hip/hip_runtime.h>

// Problem constants
constexpr int B_   = 32;
constexpr int S_   = 512;
constexpr int T_   = 512;
constexpr int ENC_ = 512;
constexpr int ATT_ = 128;
constexpr int PO_  = 256;
constexpr int DEC_ = 1024;
constexpr int M_   = 128;

// Output offsets (floats)
constexpr int MEL_OFF  = 0;
constexpr int STOP_OFF = B_*T_*M_;            // 2,097,152
constexpr int AW_OFF   = STOP_OFF + B_*T_;    // 2,113,536

typedef __attribute__((ext_vector_type(8))) short bf16x8;
typedef __attribute__((ext_vector_type(4))) float f32x4;
typedef unsigned long long ull;

__device__ __forceinline__ float frcp(float x){ return __builtin_amdgcn_rcpf(x); }
__device__ __forceinline__ float ftanh(float x){ float e = __expf(2.f*x); return 1.f - 2.f*frcp(e + 1.f); }
__device__ __forceinline__ float fsig(float x){ return frcp(1.f + __expf(-x)); }

__device__ __forceinline__ float2 upk2(unsigned u){
    return make_float2(__builtin_bit_cast(float, u << 16),
                       __builtin_bit_cast(float, u & 0xffff0000u));
}
__device__ __forceinline__ unsigned short f2b(float f){
    unsigned u = __builtin_bit_cast(unsigned, f);
    return (unsigned short)((u + 0x7fffu + ((u >> 16) & 1u)) >> 16);
}
__device__ __forceinline__ unsigned pk2(float a, float b){
    return (unsigned)f2b(a) | ((unsigned)f2b(b) << 16);
}

// ---- relaxed agent-scope (device-coherent) accessors (R3/R8-proven) ----------
__device__ __forceinline__ float ald(const float* p){
    return __hip_atomic_load(p, __ATOMIC_RELAXED, __HIP_MEMORY_SCOPE_AGENT);
}
__device__ __forceinline__ ull ald64(const void* p){
    return __hip_atomic_load((const ull*)p, __ATOMIC_RELAXED, __HIP_MEMORY_SCOPE_AGENT);
}
__device__ __forceinline__ unsigned aldu(const unsigned* p){
    return __hip_atomic_load(p, __ATOMIC_RELAXED, __HIP_MEMORY_SCOPE_AGENT);
}
__device__ __forceinline__ void astf(float* p, float v){
    __hip_atomic_store(p, v, __ATOMIC_RELAXED, __HIP_MEMORY_SCOPE_AGENT);
}
union F2U { float2 f; ull u; };
__device__ __forceinline__ void ast2f(float* p, float a, float b){
    F2U x; x.f = make_float2(a, b);
    __hip_atomic_store((ull*)p, x.u, __ATOMIC_RELAXED, __HIP_MEMORY_SCOPE_AGENT);
}
__device__ __forceinline__ void astu(unsigned* p, unsigned v){
    __hip_atomic_store(p, v, __ATOMIC_RELAXED, __HIP_MEMORY_SCOPE_AGENT);
}

// ---- point-to-point flag sync, packed stride-4 (4 flags/16B, 16 lines/64) ----
__device__ __forceinline__ void waitP64(const unsigned* f, unsigned ep){
    if (threadIdx.x < 64){
        for (;;){
            unsigned v = aldu(&f[threadIdx.x*4]);
            if (__all(v >= ep)) break;
            __builtin_amdgcn_s_sleep(2);
        }
    }
    __syncthreads();
}
__device__ __forceinline__ void waitP128(const unsigned* f, unsigned ep){
    if (threadIdx.x < 64){
        for (;;){
            unsigned a = aldu(&f[threadIdx.x*4]);
            unsigned b = aldu(&f[(threadIdx.x + 64)*4]);
            unsigned m = a < b ? a : b;
            if (__all(m >= ep)) break;
            __builtin_amdgcn_s_sleep(2);
        }
    }
    __syncthreads();
}
__device__ __forceinline__ void signalF(unsigned* f, unsigned v){
    asm volatile("s_waitcnt vmcnt(0) lgkmcnt(0)" ::: "memory");
    __syncthreads();
    if (threadIdx.x == 0) astu(f, v);
}

__device__ __forceinline__ f32x4 mfma16(bf16x8 a, bf16x8 b, f32x4 c){
    return __builtin_amdgcn_mfma_f32_16x16x32_bf16(a, b, c, 0, 0, 0);
}

// ================= prep: staged layouts =================
__global__ __launch_bounds__(256) void k_prep_w(const float* __restrict__ enc,
        const float* __restrict__ whh, const float* __restrict__ wih,
        const float* __restrict__ awd, const float* __restrict__ oww,
        unsigned short* __restrict__ enc_b, unsigned short* __restrict__ wgh,
        unsigned short* __restrict__ wgx, unsigned short* __restrict__ wgc,
        unsigned short* __restrict__ ow_b, float* __restrict__ wdT32){
    long long idx = (long long)blockIdx.x*256 + threadIdx.x;
    if (idx < 8388608LL){
        int bh = (int)(idx >> 17); int r = (int)(idx & 131071);
        int s = r >> 9, e = r & 511;
        int b = bh >> 1, half = bh & 1;
        enc_b[idx] = f2b(enc[((size_t)b*S_ + half*256 + s)*ENC_ + e]);
    } else if (idx < 11534336LL){
        long long q = idx - 8388608LL;
        int ds = (int)(q / 98304); int r = (int)(q % 98304);
        int jc = r / 16384; int r2 = r % 16384;
        int kc = r2 >> 9, l = (r2 >> 3) & 63, e = r2 & 7;
        int j = (jc >> 1)*1024 + ds*32 + (jc & 1)*16 + (l & 15);
        int k = kc*32 + ((l >> 4) << 3) + e;
        wgh[q] = f2b(whh[(size_t)j*DEC_ + k]);
    } else if (idx < 12320768LL){
        long long q = idx - 11534336LL;
        int ds = (int)(q / 24576); int r = (int)(q % 24576);
        int jc = r / 4096; int r3 = r % 4096;
        int kc = r3 >> 9, l = (r3 >> 3) & 63, e = r3 & 7;
        int j = (jc >> 1)*1024 + ds*32 + (jc & 1)*16 + (l & 15);
        int k = kc*32 + ((l >> 4) << 3) + e;
        wgx[q] = f2b(wih[(size_t)j*768 + k]);
    } else if (idx < 13893632LL){
        long long q = idx - 12320768LL;
        int ds = (int)(q / 49152); int r = (int)(q % 49152);
        int jc = r / 8192; int r3 = r % 8192;
        int kc = r3 >> 9, l = (r3 >> 3) & 63, e = r3 & 7;
        int j = (jc >> 1)*1024 + ds*32 + (jc & 1)*16 + (l & 15);
        int k = kc*32 + ((l >> 4) << 3) + e;
        wgc[q] = f2b(wih[(size_t)j*768 + 256 + k]);
    } else if (idx < 14090240LL){
        long long q = idx - 13893632LL;
        int cg = (int)(q / 49152); int r = (int)(q % 49152);
        int oc = r / 1536, k = r % 1536;
        ow_b[q] = f2b(oww[(size_t)k*M_ + cg*32 + oc]);
    } else if (idx < 14221312LL){
        long long q = idx - 14090240LL;
        int a = (int)(q >> 10), k = (int)(q & 1023);
        wdT32[q] = awd[(size_t)k*M_ + a];
    }
}

// ep_b[b][512 s][128 a] bf16 = enc @ att_we + be
__global__ __launch_bounds__(256) void k_encproj(const float* __restrict__ enc,
        const float* __restrict__ we, const float* __restrict__ be,
        unsigned short* __restrict__ ep_b){
    __shared__ float we_s[64*128];
    __shared__ float enc_s[64*64];
    int blk = blockIdx.x, tid = threadIdx.x;
    int b = blk >> 3, ss = blk & 7;
    int s = tid >> 2, ag = tid & 3;
    float acc[32];
    #pragma unroll
    for (int j = 0; j < 32; ++j) acc[j] = 0.f;
    for (int kc = 0; kc < 8; ++kc){
        __syncthreads();
        for (int i = tid; i < 8192; i += 256)
            we_s[i] = we[(size_t)(kc*64 + (i >> 7))*ATT_ + (i & 127)];
        for (int i = tid; i < 4096; i += 256)
            enc_s[i] = enc[((size_t)b*S_ + ss*64 + (i >> 6))*ENC_ + kc*64 + (i & 63)];
        __syncthreads();
        for (int kk = 0; kk < 64; ++kk){
            float ev = enc_s[s*64 + kk];
            const float* wr = &we_s[(kk << 7) + (ag << 5)];
            #pragma unroll
            for (int j = 0; j < 32; ++j) acc[j] += ev*wr[j];
        }
    }
    #pragma unroll
    for (int j = 0; j < 32; ++j){
        int a = (ag << 5) + j;
        ep_b[((size_t)b*512 + ss*64 + s)*ATT_ + a] = f2b(acc[j] + be[a]);
    }
}

// PreNet (f32 math, bf16 output)
__global__ __launch_bounds__(128) void k_prenet(const float* __restrict__ tm,
        const float* __restrict__ w1, const float* __restrict__ b1,
        const float* __restrict__ w2, const float* __restrict__ b2,
        unsigned short* __restrict__ xall){
    __shared__ float mel_l[128*20];
    __shared__ float h1_l[256*20];
    int row0 = blockIdx.x << 4;
    int t = row0 >> 5, b0 = row0 & 31;
    int tid = threadIdx.x;
    for (int p = 0; p < 16; p++){
        int idx = tid + (p << 7);
        int k = idx & 127, r = idx >> 7;
        float v = 0.f;
        if (t > 0) v = tm[((size_t)(b0 + r)*T_ + (t - 1))*M_ + k];
        mel_l[k*20 + r] = v;
    }
    __syncthreads();
    float acc1[16], acc2[16];
    #pragma unroll
    for (int i = 0; i < 16; i++){ acc1[i] = 0.f; acc2[i] = 0.f; }
    for (int k = 0; k < M_; k++){
        float wa = w1[k*256 + tid];
        float wb = w1[k*256 + tid + 128];
        float mv[16];
        *(float4*)&mv[0]  = *(const float4*)&mel_l[k*20 + 0];
        *(float4*)&mv[4]  = *(const float4*)&mel_l[k*20 + 4];
        *(float4*)&mv[8]  = *(const float4*)&mel_l[k*20 + 8];
        *(float4*)&mv[12] = *(const float4*)&mel_l[k*20 + 12];
        #pragma unroll
        for (int r = 0; r < 16; r++){ acc1[r] += mv[r]*wa; acc2[r] += mv[r]*wb; }
    }
    float bb1a = b1[tid], bb1b = b1[tid + 128];
    #pragma unroll
    for (int r = 0; r < 16; r++){
        h1_l[tid*20 + r]         = fmaxf(acc1[r] + bb1a, 0.f);
        h1_l[(tid + 128)*20 + r] = fmaxf(acc2[r] + bb1b, 0.f);
    }
    __syncthreads();
    #pragma unroll
    for (int i = 0; i < 16; i++){ acc1[i] = 0.f; acc2[i] = 0.f; }
    for (int k = 0; k < 256; k++){
        float wa = w2[k*256 + tid];
        float wb = w2[k*256 + tid + 128];
        float mv[16];
        *(float4*)&mv[0]  = *(const float4*)&h1_l[k*20 + 0];
        *(float4*)&mv[4]  = *(const float4*)&h1_l[k*20 + 4];
        *(float4*)&mv[8]  = *(const float4*)&h1_l[k*20 + 8];
        *(float4*)&mv[12] = *(const float4*)&h1_l[k*20 + 12];
        #pragma unroll
        for (int r = 0; r < 16; r++){ acc1[r] += mv[r]*wa; acc2[r] += mv[r]*wb; }
    }
    float bb2a = b2[tid], bb2b = b2[tid + 128];
    #pragma unroll
    for (int r = 0; r < 16; r++){
        xall[((size_t)row0 + r)*PO_ + tid]       = f2b(fmaxf(acc1[r] + bb2a, 0.f));
        xall[((size_t)row0 + r)*PO_ + tid + 128] = f2b(fmaxf(acc2[r] + bb2b, 0.f));
    }
}

// ================= persistent dataflow decoder =================
#define DYN_BYTES 110592

struct KP {
    const unsigned short* xall_b; const unsigned short* enc_b; const unsigned short* ep_b;
    const unsigned short* wgh; const unsigned short* wgx; const unsigned short* wgc;
    const unsigned short* ow_b;
    const float* wdT32; const float* sw; const float* bd; const float* av; const float* avb;
    const float* bih; const float* bhh; const float* p_ob; const float* p_sb;
    float* h_f32; unsigned short* h_fb;
    unsigned short* ctx_b; float* den; float* es_b;
    unsigned* gflag; unsigned* aflag; unsigned* mflag; float* out;
};

__global__ __launch_bounds__(1024) void k_persist(KP p){
    extern __shared__ char sm[];
    const int bid = blockIdx.x, tid = threadIdx.x;
    const int lane = tid & 63;

    if (bid < 64){
        // ======== GATE (XCD-affinity mapping, R11-proven) ========
        const int xcd = bid & 7, slot8 = bid >> 3;
        const int ds = xcd*4 + (slot8 >> 1), bh = slot8 & 1;
        unsigned short* hf_b = (unsigned short*)sm;            // r1 32KB (alias cf)
        char* cf = sm;                                         // r2 ctx frags 16KB
        float* pgh_l = (float*)(sm + 32768);                   // [2*16][100]
        float* pgx_l = (float*)(sm + 45568);                   // [2*16][100]
        float* pgc_l = (float*)(sm + 58368);                   // [2*16][100]
        float* rden_l= (float*)(sm + 73216);                   // 16 f
        float h_reg = 0.f;

        for (int t = 0; t < T_; ++t){
            // ---- r1: full-K gh + gix MFMA (needs h(t) from all GATE) --------
            waitP64(p.gflag, (unsigned)t);
            {
                const ull* shb = (const ull*)p.h_fb + (size_t)(t & 1)*8192;
                for (int i = tid; i < 4096; i += 1024){
                    int u = i & 1, l = (i >> 1) & 63, kc = i >> 7;
                    ((ull*)hf_b)[i] = ald64(&shb[(((size_t)bh*32 + kc)*64 + l)*2 + u]);
                }
                __syncthreads();
                int w = tid >> 6;
                if (w < 12){
                    int jc = w >> 1, kg = w & 1;
                    int r4 = lane >> 4, c16 = lane & 15;
                    const bf16x8* Bh = (const bf16x8*)p.wgh +
                        ((size_t)(ds*6 + jc)*32)*64 + lane;
                    f32x4 acc = {0.f,0.f,0.f,0.f};
                    #pragma unroll
                    for (int c = 0; c < 16; ++c){
                        int kc = kg*16 + c;
                        bf16x8 a = *(const bf16x8*)(hf_b + ((kc*64 + lane) << 3));
                        acc = mfma16(a, Bh[kc*64], acc);
                    }
                    #pragma unroll
                    for (int r = 0; r < 4; ++r)
                        pgh_l[(kg*16 + r4*4 + r)*100 + jc*16 + c16] = acc[r];
                    const bf16x8* Xp = (const bf16x8*)p.wgx +
                        ((size_t)(ds*6 + jc)*8)*64 + lane;
                    f32x4 ax = {0.f,0.f,0.f,0.f};
                    #pragma unroll
                    for (int c = 0; c < 4; ++c){
                        int kc = kg*4 + c;
                        bf16x8 a = *(const bf16x8*)(p.xall_b +
                            ((size_t)t*32 + bh*16 + c16)*256 + kc*32 + r4*8);
                        ax = mfma16(a, Xp[kc*64], ax);
                    }
                    #pragma unroll
                    for (int r = 0; r < 4; ++r)
                        pgx_l[(kg*16 + r4*4 + r)*100 + jc*16 + c16] = ax[r];
                }
                __syncthreads();
            }
            // ---- r2: gic MFMA + gates + h (needs ctx(t) from ATT) -----------
            waitP64(p.aflag, (unsigned)(t + 1));
            {
                const int slot = t & 3;
                if (tid < 16){
                    int b = bh*16 + tid;
                    rden_l[tid] = frcp(ald(&p.den[slot*64 + b]) +
                                       ald(&p.den[slot*64 + 32 + b]));
                }
                __syncthreads();
                {   // stage normalized ctx as bf16 A-frags
                    int i = tid;
                    int kc = i >> 6, l = i & 63;
                    int b = bh*16 + (l & 15);
                    int e0 = kc*32 + ((l >> 4) << 3);
                    const ull* c0 = (const ull*)p.ctx_b + (((size_t)slot*2 + 0)*32 + b)*128 + (e0 >> 2);
                    const ull* c1 = (const ull*)p.ctx_b + (((size_t)slot*2 + 1)*32 + b)*128 + (e0 >> 2);
                    ull u00 = ald64(c0), u01 = ald64(c0 + 1);
                    ull u10 = ald64(c1), u11 = ald64(c1 + 1);
                    float rd = rden_l[l & 15];
                    uint2 x0 = __builtin_bit_cast(uint2, u00);
                    uint2 x1 = __builtin_bit_cast(uint2, u01);
                    uint2 y0 = __builtin_bit_cast(uint2, u10);
                    uint2 y1 = __builtin_bit_cast(uint2, u11);
                    float2 a0 = upk2(x0.x), b0 = upk2(y0.x);
                    float2 a1 = upk2(x0.y), b1 = upk2(y0.y);
                    float2 a2 = upk2(x1.x), b2 = upk2(y1.x);
                    float2 a3 = upk2(x1.y), b3 = upk2(y1.y);
                    unsigned w0 = pk2((a0.x + b0.x)*rd, (a0.y + b0.y)*rd);
                    unsigned w1 = pk2((a1.x + b1.x)*rd, (a1.y + b1.y)*rd);
                    unsigned w2 = pk2((a2.x + b2.x)*rd, (a2.y + b2.y)*rd);
                    unsigned w3 = pk2((a3.x + b3.x)*rd, (a3.y + b3.y)*rd);
                    *(uint4*)(cf + (size_t)i*16) = make_uint4(w0, w1, w2, w3);
                }
                __syncthreads();
                int w = tid >> 6;
                if (w < 12){
                    int jc = w >> 1, kg = w & 1;
                    int r4 = lane >> 4, c16 = lane & 15;
                    const bf16x8* Cp = (const bf16x8*)p.wgc +
                        ((size_t)(ds*6 + jc)*16)*64 + lane;
                    f32x4 acc = {0.f,0.f,0.f,0.f};
                    #pragma unroll
                    for (int c = 0; c < 8; ++c){
                        int kc = kg*8 + c;
                        bf16x8 a = *(const bf16x8*)(cf + ((kc*64 + lane) << 4));
                        acc = mfma16(a, Cp[kc*64], acc);
                    }
                    #pragma unroll
                    for (int r = 0; r < 4; ++r)
                        pgc_l[(kg*16 + r4*4 + r)*100 + jc*16 + c16] = acc[r];
                }
                __syncthreads();
                if (tid < 512){
                    int b16 = tid >> 5, dl = tid & 31;
                    int dglob = ds*32 + dl;
                    const float* pa = pgh_l + b16*100;
                    const float* pb = pgh_l + (16 + b16)*100;
                    const float* xa = pgx_l + b16*100;
                    const float* xb = pgx_l + (16 + b16)*100;
                    const float* ca = pgc_l + b16*100;
                    const float* cb = pgc_l + (16 + b16)*100;
                    float gi_r = xa[dl]      + xb[dl]      + ca[dl]      + cb[dl]      + p.bih[dglob];
                    float gi_z = xa[32 + dl] + xb[32 + dl] + ca[32 + dl] + cb[32 + dl] + p.bih[1024 + dglob];
                    float gi_n = xa[64 + dl] + xb[64 + dl] + ca[64 + dl] + cb[64 + dl] + p.bih[2048 + dglob];
                    float gh_r = pa[dl]      + pb[dl]      + p.bhh[dglob];
                    float gh_z = pa[32 + dl] + pb[32 + dl] + p.bhh[1024 + dglob];
                    float gh_n = pa[64 + dl] + pb[64 + dl] + p.bhh[2048 + dglob];
                    float rr = fsig(gi_r + gh_r);
                    float zz = fsig(gi_z + gh_z);
                    float nn = ftanh(gi_n + rr*gh_n);
                    float hv = (1.f - zz)*nn + zz*h_reg;
                    h_reg = hv;
                    float hv1 = __shfl_xor(hv, 1);
                    if (!(dl & 1)){
                        int b = bh*16 + b16;
                        ast2f(&p.h_f32[(size_t)((t + 1) & 3)*32768 + (size_t)b*1024 + dglob], hv, hv1);
                        unsigned pkv = pk2(hv, hv1);
                        int l2 = ((dl >> 3) << 4) + b16;
                        size_t fo = (size_t)((t + 1) & 1)*16384 +
                                    (((size_t)bh*32 + ds)*64 + l2)*4 + ((dl & 7) >> 1);
                        astu((unsigned*)p.h_fb + fo, pkv);
                    }
                }
            }
            signalF(&p.gflag[bid*4], (unsigned)(t + 1));
        }
    } else if (bid < 128){
        // ================= ATT (b, half) =================
        const int aa = bid - 64, b = aa >> 1, half = aa & 1;
        unsigned short* ep_l = (unsigned short*)sm;          // stride-66 rows, 67584B
        float* red  = (float*)(sm + 67584);                  // [16][522]
        float* sred = (float*)(sm + 100992);                 // 4096 (aliases h_lf)
        float* h_lf = (float*)(sm + 100992);                 // 1024 f (pre-score phase)
        float* dpl  = (float*)(sm + 105088);                 // 512
        float* avl  = (float*)(sm + 105600);                 // 512
        float* esl  = (float*)(sm + 106112);                 // 1024
        float* eslt = (float*)(sm + 107136);                 // [16][17]
        {
            const ull* src = (const ull*)(p.ep_b + ((size_t)b*512 + half*256)*128);
            for (int i = tid; i < 8192; i += 1024){
                int row = i >> 5, col = i & 31;
                ((ull*)ep_l)[(size_t)row*33 + col] = src[i];
            }
            if (tid < 128) avl[tid] = p.av[tid];
        }
        __syncthreads();
        for (int t = 0; t < T_; ++t){
            waitP64(p.gflag, (unsigned)t);                 // h(t) ready
            if (t >= 3) waitP128(p.mflag, (unsigned)(t - 2));  // slot-reuse guard
            const int slot = t & 3;
            // ---- local dproj: h(t) for this b  @ wdT32 (L2-resident) --------
            if (tid < 512)
                ((ull*)h_lf)[tid] = ald64((const ull*)p.h_f32 +
                    (size_t)(t & 3)*16384 + (size_t)b*512 + tid);
            __syncthreads();
            {
                int a = tid & 127, kg = tid >> 7;
                const float* hw = h_lf + kg*128;
                const float* wr = p.wdT32 + (size_t)a*1024 + kg*128;
                float s = 0.f;
                #pragma unroll 8
                for (int i = 0; i < 128; i += 4){
                    float4 h4 = *(const float4*)(hw + i);
                    float4 w4 = *(const float4*)(wr + i);
                    s += h4.x*w4.x + h4.y*w4.y + h4.z*w4.z + h4.w*w4.w;
                }
                red[kg*128 + a] = s;
            }
            __syncthreads();
            if (tid < 128){
                float s = p.bd[tid];
                #pragma unroll
                for (int g = 0; g < 8; ++g) s += red[g*128 + tid];
                dpl[tid] = s;
            }
            __syncthreads();
            {   // scores: b64 reads from stride-66 ep_l (2-way = free)
                int s = tid >> 2, ao = tid & 3;
                const ull* er = (const ull*)ep_l + (size_t)s*33 + ao*8;
                float sc = 0.f;
                #pragma unroll
                for (int i = 0; i < 8; ++i){
                    uint2 uu = __builtin_bit_cast(uint2, er[i]);
                    float2 e0 = upk2(uu.x), e1 = upk2(uu.y);
                    int a0 = ao*32 + i*4;
                    sc += ftanh(e0.x + dpl[a0])*avl[a0]
                        + ftanh(e0.y + dpl[a0+1])*avl[a0+1]
                        + ftanh(e1.x + dpl[a0+2])*avl[a0+2]
                        + ftanh(e1.y + dpl[a0+3])*avl[a0+3];
                }
                sred[tid] = sc;
            }
            __syncthreads();
            if (tid < 256){
                float sc = sred[tid*4] + sred[tid*4+1] + sred[tid*4+2] + sred[tid*4+3] + p.avb[0];
                float ev = __expf(sc);
                esl[tid] = ev;
                eslt[(tid & 15)*17 + (tid >> 4)] = ev;
                astf(&p.es_b[(size_t)slot*16384 + b*512 + half*256 + tid], ev);
            }
            __syncthreads();
            if (tid < 64){
                float d = esl[tid*4] + esl[tid*4+1] + esl[tid*4+2] + esl[tid*4+3];
                #pragma unroll
                for (int m = 1; m <= 32; m <<= 1) d += __shfl_xor(d, m);
                if (tid == 0) astf(&p.den[slot*64 + half*32 + b], d);
            }
            {   // ctx partials: conflict-free transposed es reads
                int eo = tid >> 4, sg = tid & 15;
                int e8 = eo*8;
                const unsigned short* eb = p.enc_b + ((size_t)b*2 + half)*131072;
                float a0=0,a1=0,a2=0,a3=0,a4=0,a5=0,a6=0,a7=0;
                #pragma unroll 4
                for (int i = 0; i < 16; ++i){
                    int s = sg*16 + i;
                    float ev = eslt[i*17 + sg];
                    uint4 u = *(const uint4*)(eb + (size_t)s*512 + e8);
                    float2 v0=upk2(u.x), v1=upk2(u.y), v2=upk2(u.z), v3=upk2(u.w);
                    a0+=ev*v0.x; a1+=ev*v0.y; a2+=ev*v1.x; a3+=ev*v1.y;
                    a4+=ev*v2.x; a5+=ev*v2.y; a6+=ev*v3.x; a7+=ev*v3.y;
                }
                float* rr = &red[sg*522 + e8];
                rr[0]=a0; rr[1]=a1; rr[2]=a2; rr[3]=a3;
                rr[4]=a4; rr[5]=a5; rr[6]=a6; rr[7]=a7;
            }
            __syncthreads();
            if (tid < 512){
                float c = 0.f;
                #pragma unroll
                for (int sg = 0; sg < 16; ++sg) c += red[sg*522 + tid];
                float c1 = __shfl_xor(c, 1);
                if (!(tid & 1))
                    astu((unsigned*)p.ctx_b + (((size_t)slot*2 + half)*32 + b)*256 + (tid >> 1),
                         pk2(c, c1));
            }
            signalF(&p.aflag[aa*4], (unsigned)(t + 1));
        }
    } else {
        // ================= MEL (b, q): slack-buffered, off critical path =====
        const int m = bid - 128, b = m >> 2, q = m & 3;
        unsigned short* ow_l = (unsigned short*)sm;   // [32 oc][1538]
        float* dout = (float*)(sm + 98432);           // 1536 f
        float* redm = (float*)(sm + 104576);          // [32][33]
        float* rdm  = (float*)(sm + 108800);
        float* stpr = (float*)(sm + 108816);          // 8 f
        {
            const ull* src = (const ull*)p.ow_b + (size_t)q*12288;
            for (int i = tid; i < 12288; i += 1024){
                int oc = i / 384, kq = i - oc*384;
                uint2 u = __builtin_bit_cast(uint2, src[i]);
                unsigned* d = (unsigned*)ow_l + (size_t)oc*769 + kq*2;
                d[0] = u.x; d[1] = u.y;
            }
        }
        __syncthreads();
        for (int t = 1; t <= T_; ++t){
            waitP64(p.gflag, (unsigned)t);    // h(t) ready
            waitP64(p.aflag, (unsigned)t);    // ctx(t-1)/den/es ready
            const int slot = (t - 1) & 3;
            if (tid < 512){
                ull u = ald64((const ull*)p.h_f32 + (size_t)(t & 3)*16384 + (size_t)b*512 + tid);
                *(float2*)&dout[tid*2] = __builtin_bit_cast(float2, u);
            } else if (tid < 768){
                int i = tid - 512;
                unsigned u0 = aldu((const unsigned*)p.ctx_b + (((size_t)slot*2 + 0)*32 + b)*256 + i);
                unsigned u1 = aldu((const unsigned*)p.ctx_b + (((size_t)slot*2 + 1)*32 + b)*256 + i);
                float2 f0 = upk2(u0), f1 = upk2(u1);
                *(float2*)&dout[1024 + i*2] = make_float2(f0.x + f1.x, f0.y + f1.y);
            } else if (tid == 1023){
                rdm[0] = frcp(ald(&p.den[slot*64 + b]) + ald(&p.den[slot*64 + 32 + b]));
            }
            __syncthreads();
            if (tid < 512) dout[1024 + tid] *= rdm[0];
            __syncthreads();
            {
                int kg = tid >> 5, oc = tid & 31;
                const unsigned* wr = (const unsigned*)ow_l + (size_t)oc*769 + kg*24;
                const float* dr = dout + kg*48;
                float a = 0.f;
                #pragma unroll 6
                for (int i = 0; i < 24; ++i){
                    float2 w2 = upk2(wr[i]);
                    a += dr[i*2]*w2.x + dr[i*2+1]*w2.y;
                }
                redm[kg*33 + oc] = a;
            }
            if (q == 0 && tid < 512){
                int k3 = tid*3;
                float s = dout[k3]*p.sw[k3] + dout[k3+1]*p.sw[k3+1] + dout[k3+2]*p.sw[k3+2];
                #pragma unroll
                for (int mm = 1; mm <= 32; mm <<= 1) s += __shfl_xor(s, mm);
                if ((tid & 63) == 0) stpr[tid >> 6] = s;
                float ev = ald(&p.es_b[(size_t)slot*16384 + b*512 + tid]);
                p.out[AW_OFF + ((size_t)b*T_ + (t-1))*S_ + tid] = ev*rdm[0];
            }
            __syncthreads();
            if (tid < 32){
                float a = 0.f;
                #pragma unroll
                for (int kg = 0; kg < 32; ++kg) a += redm[kg*33 + tid];
                int c = q*32 + tid;
                p.out[MEL_OFF + ((size_t)b*T_ + (t-1))*M_ + c] = a + p.p_ob[c];
            } else if (tid == 32 && q == 0){
                float tot = 0.f;
                #pragma unroll
                for (int w2 = 0; w2 < 8; ++w2) tot += stpr[w2];
                p.out[STOP_OFF + (size_t)b*T_ + (t-1)] = tot + p.p_sb[0];
            }
            signalF(&p.mflag[m*4], (unsigned)t);
        }
    }
}

extern "C" void kernel_launch(void* const* d_in, const int* in_sizes, int n_in,
                              void* d_out, int out_size, void* d_ws, size_t ws_size,
                              hipStream_t stream){
    const float* enc = (const float*)d_in[0];
    const float* tm  = (const float*)d_in[1];
    const float* pw1 = (const float*)d_in[2];
    const float* pb1 = (const float*)d_in[3];
    const float* pw2 = (const float*)d_in[4];
    const float* pb2 = (const float*)d_in[5];
    const float* awe = (const float*)d_in[6];
    const float* abe = (const float*)d_in[7];
    const float* awd = (const float*)d_in[8];
    const float* abd = (const float*)d_in[9];
    const float* av  = (const float*)d_in[10];
    const float* avb = (const float*)d_in[11];
    const float* wih = (const float*)d_in[12];
    const float* whh = (const float*)d_in[13];
    const float* bih = (const float*)d_in[14];
    const float* bhh = (const float*)d_in[15];
    const float* oww = (const float*)d_in[16];
    const float* obb = (const float*)d_in[17];
    const float* sww = (const float*)d_in[18];
    const float* sbb = (const float*)d_in[19];
    float* out = (float*)d_out;
    float* ws  = (float*)d_ws;

    // workspace (float offsets), ~42.5 MB
    unsigned short* xall_b = (unsigned short*)ws;                //  4,194,304 ush
    unsigned short* enc_b  = (unsigned short*)(ws + 2097152);    //  8,388,608 ush
    unsigned short* ep_b   = (unsigned short*)(ws + 6291456);    //  2,097,152 ush
    unsigned short* wgh    = (unsigned short*)(ws + 7340032);    //  3,145,728 ush
    unsigned short* wgx    = (unsigned short*)(ws + 8912896);    //    786,432 ush
    unsigned short* wgc    = (unsigned short*)(ws + 9306112);    //  1,572,864 ush
    unsigned short* ow_b   = (unsigned short*)(ws + 10092544);   //    196,608 ush
    float* h_f32 = ws + 10190848;                                //  4x 32,768 f
    unsigned short* h_fb   = (unsigned short*)(ws + 10321920);   //  2x 32,768 ush
    unsigned short* ctx_b  = (unsigned short*)(ws + 10354688);   //  4x 32,768 ush
    float* den  = ws + 10420224;                                 //  4x 64 f
    float* es_b = ws + 10420480;                                 //  4x 16,384 f
    float* wdT32 = ws + 10486016;                                //    131,072 f
    unsigned* gflag = (unsigned*)(ws + 10617088);                //  64x4 u
    unsigned* aflag = gflag + 256;                               //  64x4 u
    unsigned* mflag = aflag + 256;                               // 128x4 u

    hipMemsetAsync(h_f32, 0, (size_t)131072*4, stream);
    hipMemsetAsync(h_fb, 0, (size_t)65536*2, stream);
    hipMemsetAsync(gflag, 0, 4096, stream);

    k_prep_w<<<55552, 256, 0, stream>>>(enc, whh, wih, awd, oww,
                                        enc_b, wgh, wgx, wgc, ow_b, wdT32);
    k_encproj<<<256, 256, 0, stream>>>(enc, awe, abe, ep_b);
    k_prenet<<<1024, 128, 0, stream>>>(tm, pw1, pb1, pw2, pb2, xall_b);

    hipFuncSetAttribute((const void*)k_persist,
                        hipFuncAttributeMaxDynamicSharedMemorySize, DYN_BYTES);

    KP kp;
    kp.xall_b = xall_b; kp.enc_b = enc_b; kp.ep_b = ep_b;
    kp.wgh = wgh; kp.wgx = wgx; kp.wgc = wgc; kp.ow_b = ow_b;
    kp.wdT32 = wdT32; kp.sw = sww; kp.bd = abd; kp.av = av; kp.avb = avb;
    kp.bih = bih; kp.bhh = bhh; kp.p_ob = obb; kp.p_sb = sbb;
    kp.h_f32 = h_f32; kp.h_fb = h_fb;
    kp.ctx_b = ctx_b; kp.den = den; kp.es_b = es_b;
    kp.gflag = gflag; kp.aflag = aflag; kp.mflag = mflag; kp.out = out;

    KP* kparg = &kp;
    void* args[] = { (void*)kparg };
    hipLaunchCooperativeKernel((void*)k_persist, dim3(256), dim3(1024),
                               args, DYN_BYTES, stream);
}